// Round 10
// baseline (2139.275 us; speedup 1.0000x reference)
//
#include <hip/hip_runtime.h>

typedef unsigned short u16;
using bf16x8 = __attribute__((ext_vector_type(8))) short;
using u16x8  = __attribute__((ext_vector_type(8))) unsigned short;
using u16x4  = __attribute__((ext_vector_type(4))) unsigned short;
using f32x4  = __attribute__((ext_vector_type(4))) float;

#define NN 50000
#define NPAD 50176   // 196 * 256

__device__ __forceinline__ u16 f2b(float f) {
  union { float f; unsigned u; } x; x.f = f;
  unsigned r = x.u + 0x7fffu + ((x.u >> 16) & 1u);
  return (u16)(r >> 16);
}
__device__ __forceinline__ float b2f(u16 h) {
  union { unsigned u; float f; } x; x.u = ((unsigned)h) << 16; return x.f;
}

#define GLOAD_LDS16(g, l) __builtin_amdgcn_global_load_lds( \
    (const __attribute__((address_space(1))) unsigned int*)(g), \
    (__attribute__((address_space(3))) unsigned int*)(l), 16, 0, 0)

// ---------------- CSR build ----------------
__global__ void hist_kernel(const int* __restrict__ rows, const float* __restrict__ vals,
                            int* __restrict__ counts, float* __restrict__ rowsum, int E) {
  int e = blockIdx.x * 256 + threadIdx.x;
  if (e < E) {
    int r = rows[e];
    atomicAdd(&counts[r], 1);
    atomicAdd(&rowsum[r], vals[e]);
  }
}

__global__ void scan_bsum(const int* __restrict__ counts, int* __restrict__ bsum, int n) {
  __shared__ int s[256];
  int t = threadIdx.x;
  int gi = blockIdx.x * 256 + t;
  s[t] = (gi < n) ? counts[gi] : 0;
  __syncthreads();
  for (int d = 128; d > 0; d >>= 1) {
    if (t < d) s[t] += s[t + d];
    __syncthreads();
  }
  if (t == 0) bsum[blockIdx.x] = s[0];
}

__global__ void scan_partials(int* __restrict__ bsum, int nb) {
  __shared__ int s[256];
  int t = threadIdx.x;
  int v = (t < nb) ? bsum[t] : 0;
  s[t] = v;
  __syncthreads();
  for (int d = 1; d < 256; d <<= 1) {
    int x = (t >= d) ? s[t - d] : 0;
    __syncthreads();
    s[t] += x;
    __syncthreads();
  }
  if (t < nb) bsum[t] = s[t] - v;  // exclusive
}

__global__ void scan_final(const int* __restrict__ counts, const int* __restrict__ bsum,
                           int* __restrict__ offs, int n) {
  __shared__ int s[256];
  int t = threadIdx.x;
  int gi = blockIdx.x * 256 + t;
  int v = (gi < n) ? counts[gi] : 0;
  s[t] = v;
  __syncthreads();
  for (int d = 1; d < 256; d <<= 1) {
    int x = (t >= d) ? s[t - d] : 0;
    __syncthreads();
    s[t] += x;
    __syncthreads();
  }
  if (gi <= n) offs[gi] = bsum[blockIdx.x] + s[t] - v;
}

__global__ void scatter_kernel(const int* __restrict__ rows, const int* __restrict__ cols,
                               const float* __restrict__ vals, const int* __restrict__ offs,
                               int* __restrict__ cursor, int* __restrict__ ecol,
                               float* __restrict__ ev2, int E) {
  int e = blockIdx.x * 256 + threadIdx.x;
  if (e < E) {
    int r = rows[e];
    int p = offs[r] + atomicAdd(&cursor[r], 1);
    ecol[p] = cols[e];
    ev2[p] = vals[e];
  }
}

// ---------------- conversions ----------------
__global__ void conv_f2b4(const float* __restrict__ in, u16* __restrict__ out, int n4) {
  int i = blockIdx.x * 256 + threadIdx.x;
  if (i < n4) {
    float4 f = ((const float4*)in)[i];
    ushort4 o;
    o.x = f2b(f.x); o.y = f2b(f.y); o.z = f2b(f.z); o.w = f2b(f.w);
    ((ushort4*)out)[i] = o;
  }
}

// W [K][N] f32 -> Wt [N][K] bf16
__global__ void transpose_conv(const float* __restrict__ W, u16* __restrict__ Wt, int K, int N) {
  __shared__ float tile[32][33];
  int bx = blockIdx.x * 32;  // n
  int by = blockIdx.y * 32;  // k
  int tx = threadIdx.x;
  int ty = threadIdx.y;
  for (int i = 0; i < 32; i += 8) tile[ty + i][tx] = W[(size_t)(by + ty + i) * N + bx + tx];
  __syncthreads();
  for (int i = 0; i < 32; i += 8) Wt[(size_t)(bx + ty + i) * K + by + tx] = f2b(tile[tx][ty + i]);
}

// ---------------- GEMM 256x256, BK=64, 8 waves, 4-phase K-loop (R8 schedule) ------------
__global__ __launch_bounds__(512, 2)
void gemm256(const u16* __restrict__ A, const u16* __restrict__ Bt,
             const float* __restrict__ bias, const float* __restrict__ rowsum,
             u16* __restrict__ C, int M, int N, int K, int relu, int nbx) {
  __shared__ __align__(16) u16 As[2][256 * 64];
  __shared__ __align__(16) u16 Bs[2][256 * 64];

  // bijective XCD swizzle (m204), N-fast logical order
  const int p = blockIdx.x, total = gridDim.x;
  const int q = total >> 3, r8 = total & 7;
  const int xcd = p & 7, slot_ = p >> 3;
  const int l = (xcd < r8 ? xcd * (q + 1) : r8 * (q + 1) + (xcd - r8) * q) + slot_;
  const int bm = (l / nbx) * 256;
  const int bn = (l % nbx) * 256;

  const int tid = threadIdx.x;
  const int lane = tid & 63;
  const int wid = tid >> 6;     // 0..7
  const int wm = wid >> 2;      // 0..1  -> 128-row half
  const int wn = wid & 3;       // 0..3  -> 64-col quarter
  const int l15 = lane & 15, lg = lane >> 4;

  const int xcol = (tid & 7) ^ ((tid >> 3) & 7);
  const u16* gA = A + (size_t)(bm + (tid >> 3)) * K + xcol * 8;
  const u16* gB = Bt + (size_t)(bn + (tid >> 3)) * K + xcol * 8;
  const size_t rowstep = (size_t)64 * K;

  f32x4 acc[8][4];
#pragma unroll
  for (int i = 0; i < 8; i++)
#pragma unroll
    for (int j = 0; j < 4; j++)
#pragma unroll
      for (int k = 0; k < 4; k++) acc[i][j][k] = 0.f;

  const int NT = K >> 6;

#define SPAIR_A(kt, b, h)                                                      \
  {                                                                            \
    const u16* s_ = gA + (size_t)(kt) * 64 + (size_t)(2 * (h)) * rowstep;      \
    u16* d_ = &As[b][0] + tid * 8 + (2 * (h)) * 4096;                          \
    GLOAD_LDS16(s_, d_);                                                       \
    GLOAD_LDS16(s_ + rowstep, d_ + 4096);                                      \
  }
#define SPAIR_B(kt, b, h)                                                      \
  {                                                                            \
    const u16* s_ = gB + (size_t)(kt) * 64 + (size_t)(2 * (h)) * rowstep;      \
    u16* d_ = &Bs[b][0] + tid * 8 + (2 * (h)) * 4096;                          \
    GLOAD_LDS16(s_, d_);                                                       \
    GLOAD_LDS16(s_ + rowstep, d_ + 4096);                                      \
  }

  // prologue: fully stage tile 0
  SPAIR_A(0, 0, 0); SPAIR_A(0, 0, 1); SPAIR_B(0, 0, 0); SPAIR_B(0, 0, 1);

  for (int u = 0; u < NT; u++) {
    const int cb = u & 1;
    const u16* ab = &As[cb][0];
    const u16* bb = &Bs[cb][0];

    if (u + 1 < NT) {
      SPAIR_A(u + 1, cb ^ 1, 0);
      SPAIR_A(u + 1, cb ^ 1, 1);
      asm volatile("s_waitcnt vmcnt(4)" ::: "memory");  // tile u landed; 4 in flight
    } else {
      asm volatile("s_waitcnt vmcnt(0)" ::: "memory");
    }
    __builtin_amdgcn_s_barrier();

    bf16x8 a[4][2], bqa[2][2], bqb[2][2];

    // ---- phase 1: read A0 (m0-3) + B01 (n0-1); stage B-pair0; Q(m0-3, n0-1)
#pragma unroll
    for (int m = 0; m < 4; m++) {
      int row = wm * 128 + m * 16 + l15, r7 = row & 7;
#pragma unroll
      for (int s = 0; s < 2; s++)
        a[m][s] = *(const bf16x8*)&ab[row * 64 + ((s * 4 + lg) ^ r7) * 8];
    }
#pragma unroll
    for (int n = 0; n < 2; n++) {
      int row = wn * 64 + n * 16 + l15, r7 = row & 7;
#pragma unroll
      for (int s = 0; s < 2; s++)
        bqa[n][s] = *(const bf16x8*)&bb[row * 64 + ((s * 4 + lg) ^ r7) * 8];
    }
    if (u + 1 < NT) SPAIR_B(u + 1, cb ^ 1, 0);
    __builtin_amdgcn_s_barrier();
    __builtin_amdgcn_s_setprio(1);
#pragma unroll
    for (int m = 0; m < 4; m++)
#pragma unroll
      for (int n = 0; n < 2; n++) {
        acc[m][n] = __builtin_amdgcn_mfma_f32_16x16x32_bf16(a[m][0], bqa[n][0], acc[m][n], 0, 0, 0);
        acc[m][n] = __builtin_amdgcn_mfma_f32_16x16x32_bf16(a[m][1], bqa[n][1], acc[m][n], 0, 0, 0);
      }
    __builtin_amdgcn_s_setprio(0);
    __builtin_amdgcn_s_barrier();

    // ---- phase 2: read B23 (n2-3); stage B-pair1; Q(m0-3, n2-3)
#pragma unroll
    for (int n = 0; n < 2; n++) {
      int row = wn * 64 + (n + 2) * 16 + l15, r7 = row & 7;
#pragma unroll
      for (int s = 0; s < 2; s++)
        bqb[n][s] = *(const bf16x8*)&bb[row * 64 + ((s * 4 + lg) ^ r7) * 8];
    }
    if (u + 1 < NT) SPAIR_B(u + 1, cb ^ 1, 1);
    __builtin_amdgcn_s_barrier();
    __builtin_amdgcn_s_setprio(1);
#pragma unroll
    for (int m = 0; m < 4; m++)
#pragma unroll
      for (int n = 0; n < 2; n++) {
        acc[m][n + 2] = __builtin_amdgcn_mfma_f32_16x16x32_bf16(a[m][0], bqb[n][0], acc[m][n + 2], 0, 0, 0);
        acc[m][n + 2] = __builtin_amdgcn_mfma_f32_16x16x32_bf16(a[m][1], bqb[n][1], acc[m][n + 2], 0, 0, 0);
      }
    __builtin_amdgcn_s_setprio(0);
    __builtin_amdgcn_s_barrier();

    // ---- phase 3: read A1 (m4-7, overwrite a[]); Q(m4-7, n2-3)
#pragma unroll
    for (int m = 0; m < 4; m++) {
      int row = wm * 128 + (m + 4) * 16 + l15, r7 = row & 7;
#pragma unroll
      for (int s = 0; s < 2; s++)
        a[m][s] = *(const bf16x8*)&ab[row * 64 + ((s * 4 + lg) ^ r7) * 8];
    }
    __builtin_amdgcn_s_barrier();
    __builtin_amdgcn_s_setprio(1);
#pragma unroll
    for (int m = 0; m < 4; m++)
#pragma unroll
      for (int n = 0; n < 2; n++) {
        acc[m + 4][n + 2] = __builtin_amdgcn_mfma_f32_16x16x32_bf16(a[m][0], bqb[n][0], acc[m + 4][n + 2], 0, 0, 0);
        acc[m + 4][n + 2] = __builtin_amdgcn_mfma_f32_16x16x32_bf16(a[m][1], bqb[n][1], acc[m + 4][n + 2], 0, 0, 0);
      }
    __builtin_amdgcn_s_setprio(0);
    __builtin_amdgcn_s_barrier();

    // ---- phase 4: no reads; Q(m4-7, n0-1)  (bqa still live from phase 1)
    __builtin_amdgcn_s_setprio(1);
#pragma unroll
    for (int m = 0; m < 4; m++)
#pragma unroll
      for (int n = 0; n < 2; n++) {
        acc[m + 4][n] = __builtin_amdgcn_mfma_f32_16x16x32_bf16(a[m][0], bqa[n][0], acc[m + 4][n], 0, 0, 0);
        acc[m + 4][n] = __builtin_amdgcn_mfma_f32_16x16x32_bf16(a[m][1], bqa[n][1], acc[m + 4][n], 0, 0, 0);
      }
    __builtin_amdgcn_s_setprio(0);
  }
#undef SPAIR_A
#undef SPAIR_B

  // epilogue
  float bs[4];
#pragma unroll
  for (int n = 0; n < 4; n++) bs[n] = bias[bn + wn * 64 + n * 16 + l15];
#pragma unroll
  for (int m = 0; m < 8; m++) {
    int rowb = bm + wm * 128 + m * 16 + lg * 4;
#pragma unroll
    for (int j = 0; j < 4; j++) {
      int row = rowb + j;
      if (row < M) {
        float rs = rowsum ? rowsum[row] : 1.0f;
#pragma unroll
        for (int n = 0; n < 4; n++) {
          int col = bn + wn * 64 + n * 16 + l15;
          float v = acc[m][n][j] + rs * bs[n];
          if (relu) v = fmaxf(v, 0.f);
          C[(size_t)row * N + col] = f2b(v);
        }
      }
    }
  }
}

// ---------------- SpMM v3 (CSR, column-blocked): out[i, c0:c0+P] = sum_e val[e] * X[col[e], c0:c0+P]
// X and outp are PRE-OFFSET by the column base; stride = full row width (elements).
// One node per 64-thread block; P = 64*VEC columns per pass. Direct gathers, no LDS.
// Output stores are NON-TEMPORAL (ext_vector ptr types for the builtin): the out
// stream is never re-read here, and write-allocating it evicts L3-resident X
// (R1 counter: 1.56 GB FETCH vs 102 MB X). nt keeps X hot in L3.
template <int VEC, int RELU, int OUTF32>
__global__ __launch_bounds__(64)
void spmm3(const int* __restrict__ offs, const int* __restrict__ ecol,
           const float* __restrict__ ev, const u16* __restrict__ X,
           void* __restrict__ outp, int stride) {
  const int node = blockIdx.x;
  const int t = threadIdx.x;
  const int s0 = offs[node];
  const int e0 = offs[node + 1];
  float acc[VEC];
#pragma unroll
  for (int k = 0; k < VEC; k++) acc[k] = 0.f;
  const u16* __restrict__ Xc = X + (size_t)t * VEC;

  int j = s0;
  for (; j + 4 <= e0; j += 4) {
    const int c0 = ecol[j], c1 = ecol[j + 1], c2 = ecol[j + 2], c3 = ecol[j + 3];
    const float v0 = ev[j], v1 = ev[j + 1], v2 = ev[j + 2], v3 = ev[j + 3];
    u16 a0[VEC], a1[VEC], a2[VEC], a3[VEC];
    if constexpr (VEC == 8) {
      *(u16x8*)a0 = *(const u16x8*)(Xc + (size_t)c0 * stride);
      *(u16x8*)a1 = *(const u16x8*)(Xc + (size_t)c1 * stride);
      *(u16x8*)a2 = *(const u16x8*)(Xc + (size_t)c2 * stride);
      *(u16x8*)a3 = *(const u16x8*)(Xc + (size_t)c3 * stride);
    } else {
      *(u16x4*)a0 = *(const u16x4*)(Xc + (size_t)c0 * stride);
      *(u16x4*)a1 = *(const u16x4*)(Xc + (size_t)c1 * stride);
      *(u16x4*)a2 = *(const u16x4*)(Xc + (size_t)c2 * stride);
      *(u16x4*)a3 = *(const u16x4*)(Xc + (size_t)c3 * stride);
    }
#pragma unroll
    for (int k = 0; k < VEC; k++) acc[k] += v0 * b2f(a0[k]);
#pragma unroll
    for (int k = 0; k < VEC; k++) acc[k] += v1 * b2f(a1[k]);
#pragma unroll
    for (int k = 0; k < VEC; k++) acc[k] += v2 * b2f(a2[k]);
#pragma unroll
    for (int k = 0; k < VEC; k++) acc[k] += v3 * b2f(a3[k]);
  }
  for (; j < e0; j++) {
    const int c0 = ecol[j];
    const float v0 = ev[j];
    u16 a0[VEC];
    if constexpr (VEC == 8) {
      *(u16x8*)a0 = *(const u16x8*)(Xc + (size_t)c0 * stride);
    } else {
      *(u16x4*)a0 = *(const u16x4*)(Xc + (size_t)c0 * stride);
    }
#pragma unroll
    for (int k = 0; k < VEC; k++) acc[k] += v0 * b2f(a0[k]);
  }

  if (RELU) {
#pragma unroll
    for (int k = 0; k < VEC; k++) acc[k] = fmaxf(acc[k], 0.f);
  }
  if (OUTF32) {
    float* o = (float*)outp + (size_t)node * stride + (size_t)t * VEC;
#pragma unroll
    for (int k = 0; k < VEC; k += 4) {
      f32x4 st;
      st[0] = acc[k]; st[1] = acc[k + 1]; st[2] = acc[k + 2]; st[3] = acc[k + 3];
      __builtin_nontemporal_store(st, (f32x4*)(o + k));
    }
  } else {
    u16* o = (u16*)outp + (size_t)node * stride + (size_t)t * VEC;
    if constexpr (VEC == 8) {
      u16x8 st;
#pragma unroll
      for (int k = 0; k < 8; k++) st[k] = f2b(acc[k]);
      __builtin_nontemporal_store(st, (u16x8*)o);
    } else {
      u16x4 st;
      st[0] = f2b(acc[0]); st[1] = f2b(acc[1]); st[2] = f2b(acc[2]); st[3] = f2b(acc[3]);
      __builtin_nontemporal_store(st, (u16x4*)o);
    }
  }
}

extern "C" void kernel_launch(void* const* d_in, const int* in_sizes, int n_in,
                              void* d_out, int out_size, void* d_ws, size_t ws_size,
                              hipStream_t stream) {
  const float* fea = (const float*)d_in[0];
  const int* ei = (const int*)d_in[1];
  const float* ev = (const float*)d_in[2];
  const float* W1 = (const float*)d_in[3];
  const float* b1 = (const float*)d_in[4];
  const float* W2 = (const float*)d_in[5];
  const float* b2 = (const float*)d_in[6];
  const float* W3 = (const float*)d_in[7];
  const float* b3 = (const float*)d_in[8];
  const int E = in_sizes[1] / 2;
  const int* erow = ei;
  const int* ecol_in = ei + E;

  char* w = (char*)d_ws;
  auto alloc = [&](size_t bytes) {
    char* p = w;
    w += (bytes + 255) & ~(size_t)255;
    return p;
  };
  u16* fea_b = (u16*)alloc((size_t)NPAD * 1024 * 2);  // later reused as h2
  u16* bufB  = (u16*)alloc((size_t)NPAD * 1024 * 2);  // agg0, later t3
  u16* h1_b  = (u16*)alloc((size_t)NPAD * 2048 * 2);
  u16* t2_b  = (u16*)alloc((size_t)NPAD * 1024 * 2);
  u16* W1t = (u16*)alloc((size_t)2048 * 1024 * 2);
  u16* W2t = (u16*)alloc((size_t)1024 * 2048 * 2);
  u16* W3t = (u16*)alloc((size_t)512 * 1024 * 2);
  float* rowsum = (float*)alloc((size_t)NN * 4);
  int* counts = (int*)alloc((size_t)NN * 4);
  int* cursor = (int*)alloc((size_t)NN * 4);
  int* offs = (int*)alloc((size_t)(NN + 1) * 4);
  int* ecol = (int*)alloc((size_t)E * 4);
  float* ev2 = (float*)alloc((size_t)E * 4);
  int* bsum = (int*)alloc(256 * 4);
  (void)bsum; (void)ws_size; (void)n_in; (void)out_size;

  // zero rowsum, counts, cursor (contiguous region up to offs)
  hipMemsetAsync(rowsum, 0, (size_t)((char*)offs - (char*)rowsum), stream);

  const int eb = (E + 255) / 256;
  const int nb = (NN + 256) / 256;  // covers gi = NN inclusive
  hist_kernel<<<eb, 256, 0, stream>>>(erow, ev, counts, rowsum, E);
  scan_bsum<<<nb, 256, 0, stream>>>(counts, bsum, NN);
  scan_partials<<<1, 256, 0, stream>>>(bsum, nb);
  scan_final<<<nb, 256, 0, stream>>>(counts, bsum, offs, NN);
  scatter_kernel<<<eb, 256, 0, stream>>>(erow, ecol_in, ev, offs, cursor, ecol, ev2, E);

  conv_f2b4<<<(NN * 1024 / 4 + 255) / 256, 256, 0, stream>>>(fea, fea_b, NN * 1024 / 4);
  dim3 tb(32, 8);
  transpose_conv<<<dim3(2048 / 32, 1024 / 32), tb, 0, stream>>>(W1, W1t, 1024, 2048);
  transpose_conv<<<dim3(1024 / 32, 2048 / 32), tb, 0, stream>>>(W2, W2t, 2048, 1024);
  transpose_conv<<<dim3(512 / 32, 1024 / 32), tb, 0, stream>>>(W3, W3t, 1024, 512);

  const int MT2 = (NN + 255) / 256;  // 196
  // layer 1: agg0 = A @ fea (2 column passes of 512) ; h1 = relu(agg0 @ W1 + rowsum*b1)
  spmm3<8, 0, 0><<<NN, 64, 0, stream>>>(offs, ecol, ev2, fea_b, bufB, 1024);
  spmm3<8, 0, 0><<<NN, 64, 0, stream>>>(offs, ecol, ev2, fea_b + 512, bufB + 512, 1024);
  gemm256<<<(2048 / 256) * MT2, 512, 0, stream>>>(bufB, W1t, b1, rowsum, h1_b, NN, 2048, 1024, 1, 2048 / 256);
  // layer 2: t2 = h1 @ W2 + b2 ; h2 = relu(A @ t2) (2 column passes of 512)
  gemm256<<<(1024 / 256) * MT2, 512, 0, stream>>>(h1_b, W2t, b2, nullptr, t2_b, NN, 1024, 2048, 0, 1024 / 256);
  spmm3<8, 1, 0><<<NN, 64, 0, stream>>>(offs, ecol, ev2, t2_b, fea_b, 1024);
  spmm3<8, 1, 0><<<NN, 64, 0, stream>>>(offs, ecol, ev2, t2_b + 512, fea_b + 512, 1024);
  // layer 3: t3 = h2 @ W3 + b3 ; out = A @ t3 (2 column passes of 256, f32 out)
  gemm256<<<(512 / 256) * MT2, 512, 0, stream>>>(fea_b, W3t, b3, nullptr, bufB, NN, 512, 1024, 0, 512 / 256);
  spmm3<4, 0, 1><<<NN, 64, 0, stream>>>(offs, ecol, ev2, bufB, d_out, 512);
  spmm3<4, 0, 1><<<NN, 64, 0, stream>>>(offs, ecol, ev2, bufB + 256, (float*)d_out + 256, 512);
}

// Round 11
// 2076.847 us; speedup vs baseline: 1.0301x; 1.0301x over previous
//
#include <hip/hip_runtime.h>

typedef unsigned short u16;
using bf16x8 = __attribute__((ext_vector_type(8))) short;
using u16x8  = __attribute__((ext_vector_type(8))) unsigned short;
using u16x4  = __attribute__((ext_vector_type(4))) unsigned short;
using f32x4  = __attribute__((ext_vector_type(4))) float;

#define NN 50000
#define NPAD 50176   // 196 * 256

__device__ __forceinline__ u16 f2b(float f) {
  union { float f; unsigned u; } x; x.f = f;
  unsigned r = x.u + 0x7fffu + ((x.u >> 16) & 1u);
  return (u16)(r >> 16);
}
__device__ __forceinline__ float b2f(u16 h) {
  union { unsigned u; float f; } x; x.u = ((unsigned)h) << 16; return x.f;
}

#define GLOAD_LDS16(g, l) __builtin_amdgcn_global_load_lds( \
    (const __attribute__((address_space(1))) unsigned int*)(g), \
    (__attribute__((address_space(3))) unsigned int*)(l), 16, 0, 0)

// ---------------- CSR build ----------------
__global__ void hist_kernel(const int* __restrict__ rows, const float* __restrict__ vals,
                            int* __restrict__ counts, float* __restrict__ rowsum, int E) {
  int e = blockIdx.x * 256 + threadIdx.x;
  if (e < E) {
    int r = rows[e];
    atomicAdd(&counts[r], 1);
    atomicAdd(&rowsum[r], vals[e]);
  }
}

__global__ void scan_bsum(const int* __restrict__ counts, int* __restrict__ bsum, int n) {
  __shared__ int s[256];
  int t = threadIdx.x;
  int gi = blockIdx.x * 256 + t;
  s[t] = (gi < n) ? counts[gi] : 0;
  __syncthreads();
  for (int d = 128; d > 0; d >>= 1) {
    if (t < d) s[t] += s[t + d];
    __syncthreads();
  }
  if (t == 0) bsum[blockIdx.x] = s[0];
}

__global__ void scan_partials(int* __restrict__ bsum, int nb) {
  __shared__ int s[256];
  int t = threadIdx.x;
  int v = (t < nb) ? bsum[t] : 0;
  s[t] = v;
  __syncthreads();
  for (int d = 1; d < 256; d <<= 1) {
    int x = (t >= d) ? s[t - d] : 0;
    __syncthreads();
    s[t] += x;
    __syncthreads();
  }
  if (t < nb) bsum[t] = s[t] - v;  // exclusive
}

__global__ void scan_final(const int* __restrict__ counts, const int* __restrict__ bsum,
                           int* __restrict__ offs, int n) {
  __shared__ int s[256];
  int t = threadIdx.x;
  int gi = blockIdx.x * 256 + t;
  int v = (gi < n) ? counts[gi] : 0;
  s[t] = v;
  __syncthreads();
  for (int d = 1; d < 256; d <<= 1) {
    int x = (t >= d) ? s[t - d] : 0;
    __syncthreads();
    s[t] += x;
    __syncthreads();
  }
  if (gi <= n) offs[gi] = bsum[blockIdx.x] + s[t] - v;
}

__global__ void scatter_kernel(const int* __restrict__ rows, const int* __restrict__ cols,
                               const float* __restrict__ vals, const int* __restrict__ offs,
                               int* __restrict__ cursor, int* __restrict__ ecol,
                               float* __restrict__ ev2, int E) {
  int e = blockIdx.x * 256 + threadIdx.x;
  if (e < E) {
    int r = rows[e];
    int p = offs[r] + atomicAdd(&cursor[r], 1);
    ecol[p] = cols[e];
    ev2[p] = vals[e];
  }
}

// ---------------- conversions ----------------
__global__ void conv_f2b4(const float* __restrict__ in, u16* __restrict__ out, int n4) {
  int i = blockIdx.x * 256 + threadIdx.x;
  if (i < n4) {
    float4 f = ((const float4*)in)[i];
    ushort4 o;
    o.x = f2b(f.x); o.y = f2b(f.y); o.z = f2b(f.z); o.w = f2b(f.w);
    ((ushort4*)out)[i] = o;
  }
}

// W [K][N] f32 -> Wt [N][K] bf16
__global__ void transpose_conv(const float* __restrict__ W, u16* __restrict__ Wt, int K, int N) {
  __shared__ float tile[32][33];
  int bx = blockIdx.x * 32;  // n
  int by = blockIdx.y * 32;  // k
  int tx = threadIdx.x;
  int ty = threadIdx.y;
  for (int i = 0; i < 32; i += 8) tile[ty + i][tx] = W[(size_t)(by + ty + i) * N + bx + tx];
  __syncthreads();
  for (int i = 0; i < 32; i += 8) Wt[(size_t)(bx + ty + i) * K + by + tx] = f2b(tile[tx][ty + i]);
}

// ---------------- GEMM 256x128, BK=32, 8 waves (4m x 2n), 2 blocks/CU ------------
// C[M,N] = A[M,K] @ Bt[N,K]^T (+rowsum*bias, relu). bf16 in/out, f32 accum.
// Occupancy play: 48 KiB LDS + <=128 VGPR (launch_bounds 512,4) -> 2 blocks/CU,
// so one block's barrier/waitcnt stalls are filled by the other block's MFMA.
// Simple 2-barrier counted-vmcnt loop (R6 style). Swizzle: 16B chunk ^= (row>>1)&3
// (2-way bank aliasing = free, m136); staging pre-XORs the global source chunk.
__global__ __launch_bounds__(512, 4)
void gemm256(const u16* __restrict__ A, const u16* __restrict__ Bt,
             const float* __restrict__ bias, const float* __restrict__ rowsum,
             u16* __restrict__ C, int M, int N, int K, int relu, int nbx) {
  __shared__ __align__(16) u16 As[2][256 * 32];
  __shared__ __align__(16) u16 Bs[2][128 * 32];

  // bijective XCD swizzle (m204), N-fast logical order
  const int p = blockIdx.x, total = gridDim.x;
  const int q = total >> 3, r8 = total & 7;
  const int xcd = p & 7, slot_ = p >> 3;
  const int l = (xcd < r8 ? xcd * (q + 1) : r8 * (q + 1) + (xcd - r8) * q) + slot_;
  const int bm = (l / nbx) * 256;
  const int bn = (l % nbx) * 128;

  const int tid = threadIdx.x;
  const int lane = tid & 63;
  const int wid = tid >> 6;     // 0..7
  const int wm = wid >> 1;      // 0..3  -> 64-row block
  const int wn = wid & 1;       // 0..1  -> 64-col block
  const int l15 = lane & 15, lg = lane >> 4;

  const int trow = tid >> 2;                      // 0..127
  const int xcol = (tid & 3) ^ ((tid >> 3) & 3);  // pre-swizzled source chunk
  const u16* gA = A + (size_t)(bm + trow) * K + xcol * 8;
  const u16* gB = Bt + (size_t)(bn + trow) * K + xcol * 8;
  const size_t rowstep = (size_t)128 * K;

  f32x4 acc[4][4];
#pragma unroll
  for (int i = 0; i < 4; i++)
#pragma unroll
    for (int j = 0; j < 4; j++)
#pragma unroll
      for (int k = 0; k < 4; k++) acc[i][j][k] = 0.f;

  const int NT = K >> 5;

#define STAGE(kt, b)                                                           \
  {                                                                            \
    const u16* sa = gA + (size_t)(kt) * 32;                                    \
    u16* da = &As[b][0] + tid * 8;                                             \
    GLOAD_LDS16(sa, da);                                                       \
    GLOAD_LDS16(sa + rowstep, da + 4096);                                      \
    const u16* sb = gB + (size_t)(kt) * 32;                                    \
    GLOAD_LDS16(sb, &Bs[b][0] + tid * 8);                                      \
  }

  STAGE(0, 0);  // prologue

  for (int u = 0; u < NT; u++) {
    const int cb = u & 1;
    if (u + 1 < NT) {
      STAGE(u + 1, cb ^ 1);
      asm volatile("s_waitcnt vmcnt(3)" ::: "memory");  // tile u landed; u+1 in flight
    } else {
      asm volatile("s_waitcnt vmcnt(0)" ::: "memory");
    }
    __builtin_amdgcn_s_barrier();

    const u16* ab = &As[cb][0];
    const u16* bb = &Bs[cb][0];

    bf16x8 bfr[4];
#pragma unroll
    for (int n = 0; n < 4; n++) {
      int row = wn * 64 + n * 16 + l15;
      int s = lg ^ ((row >> 1) & 3);
      bfr[n] = *(const bf16x8*)&bb[row * 32 + s * 8];
    }
    __builtin_amdgcn_s_setprio(1);
#pragma unroll
    for (int m = 0; m < 4; m++) {
      int row = wm * 64 + m * 16 + l15;
      int s = lg ^ ((row >> 1) & 3);
      bf16x8 am = *(const bf16x8*)&ab[row * 32 + s * 8];
#pragma unroll
      for (int n = 0; n < 4; n++)
        acc[m][n] = __builtin_amdgcn_mfma_f32_16x16x32_bf16(am, bfr[n], acc[m][n], 0, 0, 0);
    }
    __builtin_amdgcn_s_setprio(0);
    asm volatile("s_waitcnt lgkmcnt(0)" ::: "memory");  // all buf-cb reads retired
    __builtin_amdgcn_s_barrier();  // release: next iter stages into buf cb
  }
#undef STAGE

  // epilogue
  float bs[4];
#pragma unroll
  for (int n = 0; n < 4; n++) bs[n] = bias[bn + wn * 64 + n * 16 + l15];
#pragma unroll
  for (int m = 0; m < 4; m++) {
    int rowb = bm + wm * 64 + m * 16 + lg * 4;
#pragma unroll
    for (int j = 0; j < 4; j++) {
      int row = rowb + j;
      if (row < M) {
        float rs = rowsum ? rowsum[row] : 1.0f;
#pragma unroll
        for (int n = 0; n < 4; n++) {
          int col = bn + wn * 64 + n * 16 + l15;
          float v = acc[m][n][j] + rs * bs[n];
          if (relu) v = fmaxf(v, 0.f);
          C[(size_t)row * N + col] = f2b(v);
        }
      }
    }
  }
}

// ---------------- SpMM v3 (CSR, column-blocked): out[i, c0:c0+P] = sum_e val[e] * X[col[e], c0:c0+P]
// X and outp are PRE-OFFSET by the column base; stride = full row width (elements).
// One node per 64-thread block; P = 64*VEC columns per pass. Direct gathers, no LDS.
// Non-temporal output stores (neutral in R10, kept: semantically free).
template <int VEC, int RELU, int OUTF32>
__global__ __launch_bounds__(64)
void spmm3(const int* __restrict__ offs, const int* __restrict__ ecol,
           const float* __restrict__ ev, const u16* __restrict__ X,
           void* __restrict__ outp, int stride) {
  const int node = blockIdx.x;
  const int t = threadIdx.x;
  const int s0 = offs[node];
  const int e0 = offs[node + 1];
  float acc[VEC];
#pragma unroll
  for (int k = 0; k < VEC; k++) acc[k] = 0.f;
  const u16* __restrict__ Xc = X + (size_t)t * VEC;

  int j = s0;
  for (; j + 4 <= e0; j += 4) {
    const int c0 = ecol[j], c1 = ecol[j + 1], c2 = ecol[j + 2], c3 = ecol[j + 3];
    const float v0 = ev[j], v1 = ev[j + 1], v2 = ev[j + 2], v3 = ev[j + 3];
    u16 a0[VEC], a1[VEC], a2[VEC], a3[VEC];
    if constexpr (VEC == 8) {
      *(u16x8*)a0 = *(const u16x8*)(Xc + (size_t)c0 * stride);
      *(u16x8*)a1 = *(const u16x8*)(Xc + (size_t)c1 * stride);
      *(u16x8*)a2 = *(const u16x8*)(Xc + (size_t)c2 * stride);
      *(u16x8*)a3 = *(const u16x8*)(Xc + (size_t)c3 * stride);
    } else {
      *(u16x4*)a0 = *(const u16x4*)(Xc + (size_t)c0 * stride);
      *(u16x4*)a1 = *(const u16x4*)(Xc + (size_t)c1 * stride);
      *(u16x4*)a2 = *(const u16x4*)(Xc + (size_t)c2 * stride);
      *(u16x4*)a3 = *(const u16x4*)(Xc + (size_t)c3 * stride);
    }
#pragma unroll
    for (int k = 0; k < VEC; k++) acc[k] += v0 * b2f(a0[k]);
#pragma unroll
    for (int k = 0; k < VEC; k++) acc[k] += v1 * b2f(a1[k]);
#pragma unroll
    for (int k = 0; k < VEC; k++) acc[k] += v2 * b2f(a2[k]);
#pragma unroll
    for (int k = 0; k < VEC; k++) acc[k] += v3 * b2f(a3[k]);
  }
  for (; j < e0; j++) {
    const int c0 = ecol[j];
    const float v0 = ev[j];
    u16 a0[VEC];
    if constexpr (VEC == 8) {
      *(u16x8*)a0 = *(const u16x8*)(Xc + (size_t)c0 * stride);
    } else {
      *(u16x4*)a0 = *(const u16x4*)(Xc + (size_t)c0 * stride);
    }
#pragma unroll
    for (int k = 0; k < VEC; k++) acc[k] += v0 * b2f(a0[k]);
  }

  if (RELU) {
#pragma unroll
    for (int k = 0; k < VEC; k++) acc[k] = fmaxf(acc[k], 0.f);
  }
  if (OUTF32) {
    float* o = (float*)outp + (size_t)node * stride + (size_t)t * VEC;
#pragma unroll
    for (int k = 0; k < VEC; k += 4) {
      f32x4 st;
      st[0] = acc[k]; st[1] = acc[k + 1]; st[2] = acc[k + 2]; st[3] = acc[k + 3];
      __builtin_nontemporal_store(st, (f32x4*)(o + k));
    }
  } else {
    u16* o = (u16*)outp + (size_t)node * stride + (size_t)t * VEC;
    if constexpr (VEC == 8) {
      u16x8 st;
#pragma unroll
      for (int k = 0; k < 8; k++) st[k] = f2b(acc[k]);
      __builtin_nontemporal_store(st, (u16x8*)o);
    } else {
      u16x4 st;
      st[0] = f2b(acc[0]); st[1] = f2b(acc[1]); st[2] = f2b(acc[2]); st[3] = f2b(acc[3]);
      __builtin_nontemporal_store(st, (u16x4*)o);
    }
  }
}

extern "C" void kernel_launch(void* const* d_in, const int* in_sizes, int n_in,
                              void* d_out, int out_size, void* d_ws, size_t ws_size,
                              hipStream_t stream) {
  const float* fea = (const float*)d_in[0];
  const int* ei = (const int*)d_in[1];
  const float* ev = (const float*)d_in[2];
  const float* W1 = (const float*)d_in[3];
  const float* b1 = (const float*)d_in[4];
  const float* W2 = (const float*)d_in[5];
  const float* b2 = (const float*)d_in[6];
  const float* W3 = (const float*)d_in[7];
  const float* b3 = (const float*)d_in[8];
  const int E = in_sizes[1] / 2;
  const int* erow = ei;
  const int* ecol_in = ei + E;

  char* w = (char*)d_ws;
  auto alloc = [&](size_t bytes) {
    char* p = w;
    w += (bytes + 255) & ~(size_t)255;
    return p;
  };
  u16* fea_b = (u16*)alloc((size_t)NPAD * 1024 * 2);  // later reused as h2
  u16* bufB  = (u16*)alloc((size_t)NPAD * 1024 * 2);  // agg0, later t3
  u16* h1_b  = (u16*)alloc((size_t)NPAD * 2048 * 2);
  u16* t2_b  = (u16*)alloc((size_t)NPAD * 1024 * 2);
  u16* W1t = (u16*)alloc((size_t)2048 * 1024 * 2);
  u16* W2t = (u16*)alloc((size_t)1024 * 2048 * 2);
  u16* W3t = (u16*)alloc((size_t)512 * 1024 * 2);
  float* rowsum = (float*)alloc((size_t)NN * 4);
  int* counts = (int*)alloc((size_t)NN * 4);
  int* cursor = (int*)alloc((size_t)NN * 4);
  int* offs = (int*)alloc((size_t)(NN + 1) * 4);
  int* ecol = (int*)alloc((size_t)E * 4);
  float* ev2 = (float*)alloc((size_t)E * 4);
  int* bsum = (int*)alloc(256 * 4);
  (void)bsum; (void)ws_size; (void)n_in; (void)out_size;

  // zero rowsum, counts, cursor (contiguous region up to offs)
  hipMemsetAsync(rowsum, 0, (size_t)((char*)offs - (char*)rowsum), stream);

  const int eb = (E + 255) / 256;
  const int nb = (NN + 256) / 256;  // covers gi = NN inclusive
  hist_kernel<<<eb, 256, 0, stream>>>(erow, ev, counts, rowsum, E);
  scan_bsum<<<nb, 256, 0, stream>>>(counts, bsum, NN);
  scan_partials<<<1, 256, 0, stream>>>(bsum, nb);
  scan_final<<<nb, 256, 0, stream>>>(counts, bsum, offs, NN);
  scatter_kernel<<<eb, 256, 0, stream>>>(erow, ecol_in, ev, offs, cursor, ecol, ev2, E);

  conv_f2b4<<<(NN * 1024 / 4 + 255) / 256, 256, 0, stream>>>(fea, fea_b, NN * 1024 / 4);
  dim3 tb(32, 8);
  transpose_conv<<<dim3(2048 / 32, 1024 / 32), tb, 0, stream>>>(W1, W1t, 1024, 2048);
  transpose_conv<<<dim3(1024 / 32, 2048 / 32), tb, 0, stream>>>(W2, W2t, 2048, 1024);
  transpose_conv<<<dim3(512 / 32, 1024 / 32), tb, 0, stream>>>(W3, W3t, 1024, 512);

  const int MT2 = (NN + 255) / 256;  // 196
  // layer 1: agg0 = A @ fea (2 column passes of 512) ; h1 = relu(agg0 @ W1 + rowsum*b1)
  spmm3<8, 0, 0><<<NN, 64, 0, stream>>>(offs, ecol, ev2, fea_b, bufB, 1024);
  spmm3<8, 0, 0><<<NN, 64, 0, stream>>>(offs, ecol, ev2, fea_b + 512, bufB + 512, 1024);
  gemm256<<<(2048 / 128) * MT2, 512, 0, stream>>>(bufB, W1t, b1, rowsum, h1_b, NN, 2048, 1024, 1, 2048 / 128);
  // layer 2: t2 = h1 @ W2 + b2 ; h2 = relu(A @ t2) (2 column passes of 512)
  gemm256<<<(1024 / 128) * MT2, 512, 0, stream>>>(h1_b, W2t, b2, nullptr, t2_b, NN, 1024, 2048, 0, 1024 / 128);
  spmm3<8, 1, 0><<<NN, 64, 0, stream>>>(offs, ecol, ev2, t2_b, fea_b, 1024);
  spmm3<8, 1, 0><<<NN, 64, 0, stream>>>(offs, ecol, ev2, t2_b + 512, fea_b + 512, 1024);
  // layer 3: t3 = h2 @ W3 + b3 ; out = A @ t3 (2 column passes of 256, f32 out)
  gemm256<<<(512 / 128) * MT2, 512, 0, stream>>>(fea_b, W3t, b3, nullptr, bufB, NN, 512, 1024, 0, 512 / 128);
  spmm3<4, 0, 1><<<NN, 64, 0, stream>>>(offs, ecol, ev2, bufB, d_out, 512);
  spmm3<4, 0, 1><<<NN, 64, 0, stream>>>(offs, ecol, ev2, bufB + 256, (float*)d_out + 256, 512);
}

// Round 12
// 1994.062 us; speedup vs baseline: 1.0728x; 1.0415x over previous
//
#include <hip/hip_runtime.h>

typedef unsigned short u16;
using bf16x8 = __attribute__((ext_vector_type(8))) short;
using u16x8  = __attribute__((ext_vector_type(8))) unsigned short;
using u16x4  = __attribute__((ext_vector_type(4))) unsigned short;
using f32x4  = __attribute__((ext_vector_type(4))) float;

#define NN 50000
#define NPAD 50176   // 196 * 256

__device__ __forceinline__ u16 f2b(float f) {
  union { float f; unsigned u; } x; x.f = f;
  unsigned r = x.u + 0x7fffu + ((x.u >> 16) & 1u);
  return (u16)(r >> 16);
}
__device__ __forceinline__ float b2f(u16 h) {
  union { unsigned u; float f; } x; x.u = ((unsigned)h) << 16; return x.f;
}

#define GLOAD_LDS16(g, l) __builtin_amdgcn_global_load_lds( \
    (const __attribute__((address_space(1))) unsigned int*)(g), \
    (__attribute__((address_space(3))) unsigned int*)(l), 16, 0, 0)

// ---------------- CSR build ----------------
__global__ void hist_kernel(const int* __restrict__ rows, const float* __restrict__ vals,
                            int* __restrict__ counts, float* __restrict__ rowsum, int E) {
  int e = blockIdx.x * 256 + threadIdx.x;
  if (e < E) {
    int r = rows[e];
    atomicAdd(&counts[r], 1);
    atomicAdd(&rowsum[r], vals[e]);
  }
}

__global__ void scan_bsum(const int* __restrict__ counts, int* __restrict__ bsum, int n) {
  __shared__ int s[256];
  int t = threadIdx.x;
  int gi = blockIdx.x * 256 + t;
  s[t] = (gi < n) ? counts[gi] : 0;
  __syncthreads();
  for (int d = 128; d > 0; d >>= 1) {
    if (t < d) s[t] += s[t + d];
    __syncthreads();
  }
  if (t == 0) bsum[blockIdx.x] = s[0];
}

__global__ void scan_partials(int* __restrict__ bsum, int nb) {
  __shared__ int s[256];
  int t = threadIdx.x;
  int v = (t < nb) ? bsum[t] : 0;
  s[t] = v;
  __syncthreads();
  for (int d = 1; d < 256; d <<= 1) {
    int x = (t >= d) ? s[t - d] : 0;
    __syncthreads();
    s[t] += x;
    __syncthreads();
  }
  if (t < nb) bsum[t] = s[t] - v;  // exclusive
}

__global__ void scan_final(const int* __restrict__ counts, const int* __restrict__ bsum,
                           int* __restrict__ offs, int n) {
  __shared__ int s[256];
  int t = threadIdx.x;
  int gi = blockIdx.x * 256 + t;
  int v = (gi < n) ? counts[gi] : 0;
  s[t] = v;
  __syncthreads();
  for (int d = 1; d < 256; d <<= 1) {
    int x = (t >= d) ? s[t - d] : 0;
    __syncthreads();
    s[t] += x;
    __syncthreads();
  }
  if (gi <= n) offs[gi] = bsum[blockIdx.x] + s[t] - v;
}

__global__ void scatter_kernel(const int* __restrict__ rows, const int* __restrict__ cols,
                               const float* __restrict__ vals, const int* __restrict__ offs,
                               int* __restrict__ cursor, int* __restrict__ ecol,
                               float* __restrict__ ev2, int E) {
  int e = blockIdx.x * 256 + threadIdx.x;
  if (e < E) {
    int r = rows[e];
    int p = offs[r] + atomicAdd(&cursor[r], 1);
    ecol[p] = cols[e];
    ev2[p] = vals[e];
  }
}

// ---------------- conversions ----------------
__global__ void conv_f2b4(const float* __restrict__ in, u16* __restrict__ out, int n4) {
  int i = blockIdx.x * 256 + threadIdx.x;
  if (i < n4) {
    float4 f = ((const float4*)in)[i];
    ushort4 o;
    o.x = f2b(f.x); o.y = f2b(f.y); o.z = f2b(f.z); o.w = f2b(f.w);
    ((ushort4*)out)[i] = o;
  }
}

// W [K][N] f32 -> Wt [N][K] bf16
__global__ void transpose_conv(const float* __restrict__ W, u16* __restrict__ Wt, int K, int N) {
  __shared__ float tile[32][33];
  int bx = blockIdx.x * 32;  // n
  int by = blockIdx.y * 32;  // k
  int tx = threadIdx.x;
  int ty = threadIdx.y;
  for (int i = 0; i < 32; i += 8) tile[ty + i][tx] = W[(size_t)(by + ty + i) * N + bx + tx];
  __syncthreads();
  for (int i = 0; i < 32; i += 8) Wt[(size_t)(bx + ty + i) * K + by + tx] = f2b(tile[tx][ty + i]);
}

// ---------------- GEMM 256x128, BK=32, 8 waves (4m x 2n), 2 blocks/CU ------------
// C[M,N] = A[M,K] @ Bt[N,K]^T (+rowsum*bias, relu). bf16 in/out, f32 accum.
// R12 deltas vs R11: (1) 3-buffer LDS ring, prefetch 2 tiles ahead, vmcnt(6) —
// each tile's staging loads get ~2 tile-windows to land; (2) vectorized epilogue
// via LDS bounce (full 64B write sectors, WRITE_SIZE 200->~105MB).
// Per-buffer layout: [0..8191] = As (256x32), [8192..12287] = Bs (128x32).
__global__ __launch_bounds__(512, 4)
void gemm256(const u16* __restrict__ A, const u16* __restrict__ Bt,
             const float* __restrict__ bias, const float* __restrict__ rowsum,
             u16* __restrict__ C, int M, int N, int K, int relu, int nbx) {
  __shared__ __align__(16) u16 lds[3][12288];  // 72 KiB

  // bijective XCD swizzle (m204), N-fast logical order
  const int p = blockIdx.x, total = gridDim.x;
  const int q = total >> 3, r8 = total & 7;
  const int xcd = p & 7, slot_ = p >> 3;
  const int l = (xcd < r8 ? xcd * (q + 1) : r8 * (q + 1) + (xcd - r8) * q) + slot_;
  const int bm = (l / nbx) * 256;
  const int bn = (l % nbx) * 128;

  const int tid = threadIdx.x;
  const int lane = tid & 63;
  const int wid = tid >> 6;     // 0..7
  const int wm = wid >> 1;      // 0..3  -> 64-row block
  const int wn = wid & 1;       // 0..1  -> 64-col block
  const int l15 = lane & 15, lg = lane >> 4;

  const int trow = tid >> 2;                      // 0..127
  const int xcol = (tid & 3) ^ ((tid >> 3) & 3);  // pre-swizzled source chunk
  const u16* gA = A + (size_t)(bm + trow) * K + xcol * 8;
  const u16* gB = Bt + (size_t)(bn + trow) * K + xcol * 8;
  const size_t rowstep = (size_t)128 * K;

  f32x4 acc[4][4];
#pragma unroll
  for (int i = 0; i < 4; i++)
#pragma unroll
    for (int j = 0; j < 4; j++)
#pragma unroll
      for (int k = 0; k < 4; k++) acc[i][j][k] = 0.f;

  const int NT = K >> 5;

#define STAGE(kt, b)                                                           \
  {                                                                            \
    const u16* sa = gA + (size_t)(kt) * 32;                                    \
    u16* da = &lds[b][0] + tid * 8;                                            \
    GLOAD_LDS16(sa, da);                                                       \
    GLOAD_LDS16(sa + rowstep, da + 4096);                                      \
    const u16* sb = gB + (size_t)(kt) * 32;                                    \
    GLOAD_LDS16(sb, &lds[b][8192] + tid * 8);                                  \
  }

  STAGE(0, 0);
  STAGE(1, 1);

  for (int u = 0; u < NT; u++) {
    const int cb = u % 3;
    if (u + 2 < NT) {
      STAGE(u + 2, (u + 2) % 3);
      asm volatile("s_waitcnt vmcnt(6)" ::: "memory");  // tile u landed; u+1,u+2 in flight
    } else if (u + 1 < NT) {
      asm volatile("s_waitcnt vmcnt(3)" ::: "memory");  // tile u landed; u+1 in flight
    } else {
      asm volatile("s_waitcnt vmcnt(0)" ::: "memory");
    }
    __builtin_amdgcn_s_barrier();

    const u16* ab = &lds[cb][0];
    const u16* bb = &lds[cb][8192];

    bf16x8 bfr[4];
#pragma unroll
    for (int n = 0; n < 4; n++) {
      int row = wn * 64 + n * 16 + l15;
      int s = lg ^ ((row >> 1) & 3);
      bfr[n] = *(const bf16x8*)&bb[row * 32 + s * 8];
    }
    __builtin_amdgcn_s_setprio(1);
#pragma unroll
    for (int m = 0; m < 4; m++) {
      int row = wm * 64 + m * 16 + l15;
      int s = lg ^ ((row >> 1) & 3);
      bf16x8 am = *(const bf16x8*)&ab[row * 32 + s * 8];
#pragma unroll
      for (int n = 0; n < 4; n++)
        acc[m][n] = __builtin_amdgcn_mfma_f32_16x16x32_bf16(am, bfr[n], acc[m][n], 0, 0, 0);
    }
    __builtin_amdgcn_s_setprio(0);
    asm volatile("s_waitcnt lgkmcnt(0)" ::: "memory");  // all buf-cb reads retired
    __builtin_amdgcn_s_barrier();  // release: buffer cb may be restaged
  }
#undef STAGE

  // ---- epilogue: LDS bounce for full-sector vectorized C stores ----
  // Final release barrier above guarantees all waves are done with staging LDS.
  // Each wave uses a private 64x64 u16 region (8 KiB): 8 waves = 64 KiB <= 72.
  u16* eb = &lds[0][0] + wid * 4096;
  float bs[4];
#pragma unroll
  for (int n = 0; n < 4; n++) bs[n] = bias[bn + wn * 64 + n * 16 + l15];
#pragma unroll
  for (int m = 0; m < 4; m++) {
    int r0 = m * 16 + lg * 4;
#pragma unroll
    for (int j = 0; j < 4; j++) {
      int r = r0 + j;
      float rs = rowsum ? rowsum[bm + wm * 64 + r] : 1.0f;
#pragma unroll
      for (int n = 0; n < 4; n++) {
        int c = n * 16 + l15;
        float v = acc[m][n][j] + rs * bs[n];
        if (relu) v = fmaxf(v, 0.f);
        int cs = (c & 7) | ((((c >> 3) ^ (r & 7)) & 7) << 3);  // chunk swizzle
        eb[r * 64 + cs] = f2b(v);
      }
    }
  }
  asm volatile("s_waitcnt lgkmcnt(0)" ::: "memory");  // wave-local writes done
#pragma unroll
  for (int pass = 0; pass < 8; pass++) {
    int r = pass * 8 + (lane >> 3);        // 0..63 within wave tile
    int ch = lane & 7;                     // logical 16B chunk
    int chs = ch ^ (r & 7);                // stored position
    u16x8 val = *(const u16x8*)&eb[r * 64 + chs * 8];
    int grow = bm + wm * 64 + r;
    if (grow < M)
      *(u16x8*)&C[(size_t)grow * N + bn + wn * 64 + ch * 8] = val;
  }
}

// ---------------- SpMM v3 (CSR, column-blocked): out[i, c0:c0+P] = sum_e val[e] * X[col[e], c0:c0+P]
// X and outp are PRE-OFFSET by the column base; stride = full row width (elements).
// One node per 64-thread block; P = 64*VEC columns per pass. Direct gathers, no LDS.
// Non-temporal output stores (neutral in R10, kept: semantically free).
template <int VEC, int RELU, int OUTF32>
__global__ __launch_bounds__(64)
void spmm3(const int* __restrict__ offs, const int* __restrict__ ecol,
           const float* __restrict__ ev, const u16* __restrict__ X,
           void* __restrict__ outp, int stride) {
  const int node = blockIdx.x;
  const int t = threadIdx.x;
  const int s0 = offs[node];
  const int e0 = offs[node + 1];
  float acc[VEC];
#pragma unroll
  for (int k = 0; k < VEC; k++) acc[k] = 0.f;
  const u16* __restrict__ Xc = X + (size_t)t * VEC;

  int j = s0;
  for (; j + 4 <= e0; j += 4) {
    const int c0 = ecol[j], c1 = ecol[j + 1], c2 = ecol[j + 2], c3 = ecol[j + 3];
    const float v0 = ev[j], v1 = ev[j + 1], v2 = ev[j + 2], v3 = ev[j + 3];
    u16 a0[VEC], a1[VEC], a2[VEC], a3[VEC];
    if constexpr (VEC == 8) {
      *(u16x8*)a0 = *(const u16x8*)(Xc + (size_t)c0 * stride);
      *(u16x8*)a1 = *(const u16x8*)(Xc + (size_t)c1 * stride);
      *(u16x8*)a2 = *(const u16x8*)(Xc + (size_t)c2 * stride);
      *(u16x8*)a3 = *(const u16x8*)(Xc + (size_t)c3 * stride);
    } else {
      *(u16x4*)a0 = *(const u16x4*)(Xc + (size_t)c0 * stride);
      *(u16x4*)a1 = *(const u16x4*)(Xc + (size_t)c1 * stride);
      *(u16x4*)a2 = *(const u16x4*)(Xc + (size_t)c2 * stride);
      *(u16x4*)a3 = *(const u16x4*)(Xc + (size_t)c3 * stride);
    }
#pragma unroll
    for (int k = 0; k < VEC; k++) acc[k] += v0 * b2f(a0[k]);
#pragma unroll
    for (int k = 0; k < VEC; k++) acc[k] += v1 * b2f(a1[k]);
#pragma unroll
    for (int k = 0; k < VEC; k++) acc[k] += v2 * b2f(a2[k]);
#pragma unroll
    for (int k = 0; k < VEC; k++) acc[k] += v3 * b2f(a3[k]);
  }
  for (; j < e0; j++) {
    const int c0 = ecol[j];
    const float v0 = ev[j];
    u16 a0[VEC];
    if constexpr (VEC == 8) {
      *(u16x8*)a0 = *(const u16x8*)(Xc + (size_t)c0 * stride);
    } else {
      *(u16x4*)a0 = *(const u16x4*)(Xc + (size_t)c0 * stride);
    }
#pragma unroll
    for (int k = 0; k < VEC; k++) acc[k] += v0 * b2f(a0[k]);
  }

  if (RELU) {
#pragma unroll
    for (int k = 0; k < VEC; k++) acc[k] = fmaxf(acc[k], 0.f);
  }
  if (OUTF32) {
    float* o = (float*)outp + (size_t)node * stride + (size_t)t * VEC;
#pragma unroll
    for (int k = 0; k < VEC; k += 4) {
      f32x4 st;
      st[0] = acc[k]; st[1] = acc[k + 1]; st[2] = acc[k + 2]; st[3] = acc[k + 3];
      __builtin_nontemporal_store(st, (f32x4*)(o + k));
    }
  } else {
    u16* o = (u16*)outp + (size_t)node * stride + (size_t)t * VEC;
    if constexpr (VEC == 8) {
      u16x8 st;
#pragma unroll
      for (int k = 0; k < 8; k++) st[k] = f2b(acc[k]);
      __builtin_nontemporal_store(st, (u16x8*)o);
    } else {
      u16x4 st;
      st[0] = f2b(acc[0]); st[1] = f2b(acc[1]); st[2] = f2b(acc[2]); st[3] = f2b(acc[3]);
      __builtin_nontemporal_store(st, (u16x4*)o);
    }
  }
}

extern "C" void kernel_launch(void* const* d_in, const int* in_sizes, int n_in,
                              void* d_out, int out_size, void* d_ws, size_t ws_size,
                              hipStream_t stream) {
  const float* fea = (const float*)d_in[0];
  const int* ei = (const int*)d_in[1];
  const float* ev = (const float*)d_in[2];
  const float* W1 = (const float*)d_in[3];
  const float* b1 = (const float*)d_in[4];
  const float* W2 = (const float*)d_in[5];
  const float* b2 = (const float*)d_in[6];
  const float* W3 = (const float*)d_in[7];
  const float* b3 = (const float*)d_in[8];
  const int E = in_sizes[1] / 2;
  const int* erow = ei;
  const int* ecol_in = ei + E;

  char* w = (char*)d_ws;
  auto alloc = [&](size_t bytes) {
    char* p = w;
    w += (bytes + 255) & ~(size_t)255;
    return p;
  };
  u16* fea_b = (u16*)alloc((size_t)NPAD * 1024 * 2);  // later reused as h2
  u16* bufB  = (u16*)alloc((size_t)NPAD * 1024 * 2);  // agg0, later t3
  u16* h1_b  = (u16*)alloc((size_t)NPAD * 2048 * 2);
  u16* t2_b  = (u16*)alloc((size_t)NPAD * 1024 * 2);
  u16* W1t = (u16*)alloc((size_t)2048 * 1024 * 2);
  u16* W2t = (u16*)alloc((size_t)1024 * 2048 * 2);
  u16* W3t = (u16*)alloc((size_t)512 * 1024 * 2);
  float* rowsum = (float*)alloc((size_t)NN * 4);
  int* counts = (int*)alloc((size_t)NN * 4);
  int* cursor = (int*)alloc((size_t)NN * 4);
  int* offs = (int*)alloc((size_t)(NN + 1) * 4);
  int* ecol = (int*)alloc((size_t)E * 4);
  float* ev2 = (float*)alloc((size_t)E * 4);
  int* bsum = (int*)alloc(256 * 4);
  (void)bsum; (void)ws_size; (void)n_in; (void)out_size;

  // zero rowsum, counts, cursor (contiguous region up to offs)
  hipMemsetAsync(rowsum, 0, (size_t)((char*)offs - (char*)rowsum), stream);

  const int eb = (E + 255) / 256;
  const int nb = (NN + 256) / 256;  // covers gi = NN inclusive
  hist_kernel<<<eb, 256, 0, stream>>>(erow, ev, counts, rowsum, E);
  scan_bsum<<<nb, 256, 0, stream>>>(counts, bsum, NN);
  scan_partials<<<1, 256, 0, stream>>>(bsum, nb);
  scan_final<<<nb, 256, 0, stream>>>(counts, bsum, offs, NN);
  scatter_kernel<<<eb, 256, 0, stream>>>(erow, ecol_in, ev, offs, cursor, ecol, ev2, E);

  conv_f2b4<<<(NN * 1024 / 4 + 255) / 256, 256, 0, stream>>>(fea, fea_b, NN * 1024 / 4);
  dim3 tb(32, 8);
  transpose_conv<<<dim3(2048 / 32, 1024 / 32), tb, 0, stream>>>(W1, W1t, 1024, 2048);
  transpose_conv<<<dim3(1024 / 32, 2048 / 32), tb, 0, stream>>>(W2, W2t, 2048, 1024);
  transpose_conv<<<dim3(512 / 32, 1024 / 32), tb, 0, stream>>>(W3, W3t, 1024, 512);

  const int MT2 = (NN + 255) / 256;  // 196
  // layer 1: agg0 = A @ fea (2 column passes of 512) ; h1 = relu(agg0 @ W1 + rowsum*b1)
  spmm3<8, 0, 0><<<NN, 64, 0, stream>>>(offs, ecol, ev2, fea_b, bufB, 1024);
  spmm3<8, 0, 0><<<NN, 64, 0, stream>>>(offs, ecol, ev2, fea_b + 512, bufB + 512, 1024);
  gemm256<<<(2048 / 128) * MT2, 512, 0, stream>>>(bufB, W1t, b1, rowsum, h1_b, NN, 2048, 1024, 1, 2048 / 128);
  // layer 2: t2 = h1 @ W2 + b2 ; h2 = relu(A @ t2) (2 column passes of 512)
  gemm256<<<(1024 / 128) * MT2, 512, 0, stream>>>(h1_b, W2t, b2, nullptr, t2_b, NN, 1024, 2048, 0, 1024 / 128);
  spmm3<8, 1, 0><<<NN, 64, 0, stream>>>(offs, ecol, ev2, t2_b, fea_b, 1024);
  spmm3<8, 1, 0><<<NN, 64, 0, stream>>>(offs, ecol, ev2, t2_b + 512, fea_b + 512, 1024);
  // layer 3: t3 = h2 @ W3 + b3 ; out = A @ t3 (2 column passes of 256, f32 out)
  gemm256<<<(512 / 128) * MT2, 512, 0, stream>>>(fea_b, W3t, b3, nullptr, bufB, NN, 512, 1024, 0, 512 / 128);
  spmm3<4, 0, 1><<<NN, 64, 0, stream>>>(offs, ecol, ev2, bufB, d_out, 512);
  spmm3<4, 0, 1><<<NN, 64, 0, stream>>>(offs, ecol, ev2, bufB + 256, (float*)d_out + 256, 512);
}